// Round 2
// baseline (219.902 us; speedup 1.0000x reference)
//
#include <hip/hip_runtime.h>

#define HEADS 8
static constexpr int BSZ = 4;
static constexpr int CCH = 512;
static constexpr int NSP = 2304;   // 48*48
static constexpr int DH  = 64;     // head dim

typedef _Float16 f16x8 __attribute__((ext_vector_type(8)));
typedef float f32x4 __attribute__((ext_vector_type(4)));
typedef unsigned short u16;
typedef unsigned int u32;

__device__ __forceinline__ u16 f2h(float f) {
  _Float16 h = (_Float16)f;          // v_cvt_f16_f32, RTNE
  return __builtin_bit_cast(u16, h);
}

__device__ __forceinline__ void gl_lds16(const void* g, void* l) {
  __builtin_amdgcn_global_load_lds(
      (const __attribute__((address_space(1))) u32*)g,
      (__attribute__((address_space(3))) u32*)l, 16, 0, 0);
}

// ---------------- kernel 1: convert weights fp32 -> fp16 ----------------
__global__ void k_cvt_w(const float* __restrict__ w0, const float* __restrict__ w1,
                        const float* __restrict__ w2, const float* __restrict__ w3,
                        u16* __restrict__ dst) {
  int wsel = blockIdx.y;
  const float* src = wsel == 0 ? w0 : wsel == 1 ? w1 : wsel == 2 ? w2 : w3;
  int i = (blockIdx.x * 256 + threadIdx.x) * 4;
  float4 v = *(const float4*)(src + i);
  ushort4 o;
  o.x = f2h(v.x); o.y = f2h(v.y); o.z = f2h(v.z); o.w = f2h(v.w);
  *(ushort4*)(dst + (size_t)wsel * CCH * CCH + i) = o;
}

// ------------- kernel 2: x (b,c,n) fp32 -> xT (b,n,c) fp16 --------------
__global__ void k_cvt_x(const float* __restrict__ x, u16* __restrict__ xT) {
  __shared__ u16 t[64][66];
  int b = blockIdx.z, c0 = blockIdx.y * 64, n0 = blockIdx.x * 64;
  int col = threadIdx.x & 63, rb = threadIdx.x >> 6;
#pragma unroll
  for (int rr = 0; rr < 16; rr++) {
    int r = rr * 4 + rb;  // c-local
    t[r][col] = f2h(x[((size_t)b * CCH + c0 + r) * NSP + n0 + col]);
  }
  __syncthreads();
#pragma unroll
  for (int rr = 0; rr < 16; rr++) {
    int r = rr * 4 + rb;  // n-local
    xT[((size_t)b * NSP + n0 + r) * CCH + c0 + col] = t[col][r];
  }
}

// ------- kernel 3: fused 4-way projection GEMM (Wq/Wk/Wv/Wsc) ----------
// C[o,n] = sum_c W[o,c] * xT[n,c].  BM=BN=128, BK=64, 4 waves (2x2 of 64x64).
__global__ __launch_bounds__(256) void k_proj(const u16* __restrict__ Wall,
    const u16* __restrict__ xT, u16* __restrict__ Qo, u16* __restrict__ Ko,
    u16* __restrict__ Vo, float* __restrict__ SCo) {
  __shared__ u16 smem[17408];          // A[128][64] | B[128][64]; reused as stash[128][136]
  u16* At = smem;
  u16* Bt = smem + 8192;
  int z = blockIdx.z, b = z >> 2, wsel = z & 3;
  int o0 = blockIdx.y * 128, n0 = blockIdx.x * 128;
  int tid = threadIdx.x, lane = tid & 63, wv = tid >> 6;
  int wr = wv >> 1, wc = wv & 1;
  const u16* Asrc = Wall + (size_t)wsel * CCH * CCH + (size_t)o0 * CCH;
  const u16* Bsrc = xT + ((size_t)b * NSP + n0) * CCH;
  f32x4 acc[4][4] = {};
  for (int kc = 0; kc < CCH; kc += 64) {
    __syncthreads();
#pragma unroll
    for (int i = 0; i < 4; i++) {
      int ch = (wv * 4 + i) * 64 + lane;          // 16B-chunk index, 1024 total
      int row = ch >> 3, cc = ch & 7;             // swizzle: chunk' = cc ^ (row&7)
      gl_lds16(Asrc + (size_t)row * CCH + kc + ((cc ^ (row & 7)) << 3), At + (wv * 4 + i) * 512);
      gl_lds16(Bsrc + (size_t)row * CCH + kc + ((cc ^ (row & 7)) << 3), Bt + (wv * 4 + i) * 512);
    }
    __syncthreads();
#pragma unroll
    for (int ks = 0; ks < 2; ks++) {
      f16x8 af[4], bfr[4];
#pragma unroll
      for (int f = 0; f < 4; f++) {
        int orow = wr * 64 + f * 16 + (lane & 15);
        int nrow = wc * 64 + f * 16 + (lane & 15);
        int k8 = (lane >> 4) + ks * 4;
        af[f]  = *(const f16x8*)(At + orow * 64 + ((k8 ^ (orow & 7)) << 3));
        bfr[f] = *(const f16x8*)(Bt + nrow * 64 + ((k8 ^ (nrow & 7)) << 3));
      }
#pragma unroll
      for (int i = 0; i < 4; i++)
#pragma unroll
        for (int j = 0; j < 4; j++)
          acc[i][j] = __builtin_amdgcn_mfma_f32_16x16x32_f16(af[i], bfr[j], acc[i][j], 0, 0, 0);
    }
  }
  if (wsel >= 2) {
    // V: fp16 natural (b, o, n); SC: fp32 -> d_out (b, c, n)
#pragma unroll
    for (int i = 0; i < 4; i++)
#pragma unroll
      for (int j = 0; j < 4; j++)
#pragma unroll
        for (int r = 0; r < 4; r++) {
          int o = o0 + wr * 64 + i * 16 + ((lane >> 4) << 2) + r;
          int n = n0 + wc * 64 + j * 16 + (lane & 15);
          size_t idx = ((size_t)b * CCH + o) * NSP + n;
          if (wsel == 3) SCo[idx] = acc[i][j][r];
          else           Vo[idx]  = f2h(acc[i][j][r]);
        }
  } else {
    // Q/K -> (b, h, n, d) via LDS transpose for coalesced 128B-row writes
    __syncthreads();
    u16* stash = smem;  // [128 n][136 o]
#pragma unroll
    for (int i = 0; i < 4; i++)
#pragma unroll
      for (int j = 0; j < 4; j++)
#pragma unroll
        for (int r = 0; r < 4; r++) {
          int ol = wr * 64 + i * 16 + ((lane >> 4) << 2) + r;
          int nl = wc * 64 + j * 16 + (lane & 15);
          stash[nl * 136 + ol] = f2h(acc[i][j][r]);
        }
    __syncthreads();
    u16* dst = wsel ? Ko : Qo;
    int hl = tid >> 7, nn = tid & 127;
    int h = (o0 >> 6) + hl;
    size_t base = ((size_t)(b * HEADS + h) * NSP + n0 + nn) * DH;
#pragma unroll
    for (int c2 = 0; c2 < 8; c2++)
      *(int4*)(dst + base + c2 * 8) = *(const int4*)(stash + nn * 136 + hl * 64 + c2 * 8);
  }
}

// ------------------- kernel 4: flash attention + epilogue ---------------
// block = (qt, b*8+h): 64 q-rows, 4 waves x 16 rows. KV streamed in 64-tiles.
__global__ __launch_bounds__(256) void k_attn(const u16* __restrict__ Qw,
    const u16* __restrict__ Kw, const u16* __restrict__ Vw,
    const float* __restrict__ gamma, float* __restrict__ out) {
  __shared__ u16 smem[12288];          // K[64][64] | V[64][64] | P 4x[16][64]
  u16* Kt = smem;
  u16* Vt = smem + 4096;
  int qt = blockIdx.x, bh = blockIdx.y;
  int b = bh >> 3, h = bh & 7;
  int n0 = qt * 64;
  int tid = threadIdx.x, lane = tid & 63, wv = tid >> 6;
  u16* Pt = smem + 8192 + wv * 1024;   // wave-private 16x64
  const u16* Qbase = Qw + ((size_t)bh * NSP + n0 + wv * 16) * DH;
  f16x8 aq[2];
#pragma unroll
  for (int ks = 0; ks < 2; ks++)
    aq[ks] = *(const f16x8*)(Qbase + (lane & 15) * DH + (lane >> 4) * 8 + ks * 32);
  const u16* Ksrc = Kw + (size_t)bh * NSP * DH;
  const u16* Vsrc = Vw + ((size_t)b * CCH + h * DH) * NSP;
  float mrun[4], lrun[4];
  f32x4 accO[4] = {};
#pragma unroll
  for (int r = 0; r < 4; r++) { mrun[r] = -__builtin_inff(); lrun[r] = 0.f; }
  for (int mt = 0; mt < NSP / 64; mt++) {
    int m0 = mt * 64;
    __syncthreads();
#pragma unroll
    for (int i = 0; i < 2; i++) {
      int ch = (wv * 2 + i) * 64 + lane;
      int row = ch >> 3, cc = ch & 7;
      gl_lds16(Ksrc + (size_t)(m0 + row) * DH + ((cc ^ (row & 7)) << 3), Kt + (wv * 2 + i) * 512);
      gl_lds16(Vsrc + (size_t)row * NSP + m0 + ((cc ^ (row & 7)) << 3), Vt + (wv * 2 + i) * 512);
    }
    __syncthreads();
    // S = Q K^T  (16 q-rows x 64 m)
    f32x4 s[4] = {};
#pragma unroll
    for (int mf = 0; mf < 4; mf++)
#pragma unroll
      for (int ks = 0; ks < 2; ks++) {
        int mrow = mf * 16 + (lane & 15);
        f16x8 bk = *(const f16x8*)(Kt + mrow * 64 + ((((lane >> 4) + ks * 4) ^ (mrow & 7)) << 3));
        s[mf] = __builtin_amdgcn_mfma_f32_16x16x32_f16(aq[ks], bk, s[mf], 0, 0, 0);
      }
    // online softmax (rows live on 16-lane groups)
    float mnew[4], scl[4];
#pragma unroll
    for (int r = 0; r < 4; r++) {
      float tm = fmaxf(fmaxf(s[0][r], s[1][r]), fmaxf(s[2][r], s[3][r]));
      tm = fmaxf(tm, __shfl_xor(tm, 1));
      tm = fmaxf(tm, __shfl_xor(tm, 2));
      tm = fmaxf(tm, __shfl_xor(tm, 4));
      tm = fmaxf(tm, __shfl_xor(tm, 8));
      mnew[r] = fmaxf(mrun[r], tm);
      scl[r] = __expf(mrun[r] - mnew[r]);
      mrun[r] = mnew[r];
    }
    float p[4][4];
#pragma unroll
    for (int mf = 0; mf < 4; mf++)
#pragma unroll
      for (int r = 0; r < 4; r++)
        p[mf][r] = __expf(s[mf][r] - mnew[r]);
#pragma unroll
    for (int r = 0; r < 4; r++) {
      float ts = (p[0][r] + p[1][r]) + (p[2][r] + p[3][r]);
      ts += __shfl_xor(ts, 1);
      ts += __shfl_xor(ts, 2);
      ts += __shfl_xor(ts, 4);
      ts += __shfl_xor(ts, 8);
      lrun[r] = lrun[r] * scl[r] + ts;
    }
#pragma unroll
    for (int df = 0; df < 4; df++)
#pragma unroll
      for (int r = 0; r < 4; r++)
        accO[df][r] *= scl[r];
    // P (D-layout) -> wave-private LDS (A-layout, swizzled)
#pragma unroll
    for (int mf = 0; mf < 4; mf++)
#pragma unroll
      for (int r = 0; r < 4; r++) {
        int q = ((lane >> 4) << 2) + r;
        int m = mf * 16 + (lane & 15);
        Pt[q * 64 + (((m >> 3) ^ (q & 7)) << 3) + (m & 7)] = f2h(p[mf][r]);
      }
    // O += P * V
    f16x8 ap[2];
#pragma unroll
    for (int ks = 0; ks < 2; ks++) {
      int qr = lane & 15;
      ap[ks] = *(const f16x8*)(Pt + qr * 64 + ((((lane >> 4) + ks * 4) ^ (qr & 7)) << 3));
    }
#pragma unroll
    for (int df = 0; df < 4; df++)
#pragma unroll
      for (int ks = 0; ks < 2; ks++) {
        int drow = df * 16 + (lane & 15);
        f16x8 bv = *(const f16x8*)(Vt + drow * 64 + ((((lane >> 4) + ks * 4) ^ (drow & 7)) << 3));
        accO[df] = __builtin_amdgcn_mfma_f32_16x16x32_f16(ap[ks], bv, accO[df], 0, 0, 0);
      }
  }
  float inv[4];
#pragma unroll
  for (int r = 0; r < 4; r++) inv[r] = 1.0f / lrun[r];
  __syncthreads();
  float* stash = (float*)smem;  // [64 d][68]
#pragma unroll
  for (int df = 0; df < 4; df++)
#pragma unroll
    for (int r = 0; r < 4; r++) {
      int d = df * 16 + (lane & 15);
      int q = wv * 16 + ((lane >> 4) << 2) + r;
      stash[d * 68 + q] = accO[df][r] * inv[r];
    }
  __syncthreads();
  int d = tid >> 2, qp = (tid & 3) * 16;
  int co = h * DH + d;
  float g = gamma[co];
  size_t obase = ((size_t)b * CCH + co) * NSP + n0 + qp;
#pragma unroll
  for (int j = 0; j < 16; j += 4) {
    f32x4 v = *(const f32x4*)(stash + d * 68 + qp + j);
    f32x4 scv = *(const f32x4*)(out + obase + j);
    v = g * v + scv;
    *(f32x4*)(out + obase + j) = v;
  }
}

extern "C" void kernel_launch(void* const* d_in, const int* in_sizes, int n_in,
                              void* d_out, int out_size, void* d_ws, size_t ws_size,
                              hipStream_t stream) {
  const float* x     = (const float*)d_in[0];
  const float* Wq    = (const float*)d_in[1];
  const float* Wk    = (const float*)d_in[2];
  const float* Wv    = (const float*)d_in[3];
  const float* Wsc   = (const float*)d_in[4];
  const float* gamma = (const float*)d_in[5];
  float* out = (float*)d_out;

  u16* xT   = (u16*)d_ws;                               // 4*2304*512
  u16* Wall = xT + (size_t)BSZ * NSP * CCH;             // 4*512*512
  u16* Qw   = Wall + (size_t)4 * CCH * CCH;             // 4*8*2304*64
  u16* Kw   = Qw + (size_t)BSZ * CCH * NSP;
  u16* Vw   = Kw + (size_t)BSZ * CCH * NSP;

  hipLaunchKernelGGL(k_cvt_w, dim3(CCH * CCH / 1024, 4), dim3(256), 0, stream,
                     Wq, Wk, Wv, Wsc, Wall);
  hipLaunchKernelGGL(k_cvt_x, dim3(NSP / 64, CCH / 64, BSZ), dim3(256), 0, stream, x, xT);
  hipLaunchKernelGGL(k_proj, dim3(NSP / 128, CCH / 128, BSZ * 4), dim3(256), 0, stream,
                     Wall, xT, Qw, Kw, Vw, out);
  hipLaunchKernelGGL(k_attn, dim3(NSP / 64, BSZ * HEADS), dim3(256), 0, stream,
                     Qw, Kw, Vw, gamma, out);
}

// Round 3
// 172.362 us; speedup vs baseline: 1.2758x; 1.2758x over previous
//
#include <hip/hip_runtime.h>

#define HEADS 8
static constexpr int BSZ = 4;
static constexpr int CCH = 512;
static constexpr int NSP = 2304;   // 48*48
static constexpr int DH  = 64;     // head dim

typedef _Float16 f16x8 __attribute__((ext_vector_type(8)));
typedef _Float16 f16x2 __attribute__((ext_vector_type(2)));
typedef float f32x4 __attribute__((ext_vector_type(4)));
typedef float f32x16 __attribute__((ext_vector_type(16)));
typedef int i32x4 __attribute__((ext_vector_type(4)));
typedef unsigned short u16;
typedef unsigned int u32;

__device__ __forceinline__ u16 f2h(float f) {
  _Float16 h = (_Float16)f;
  return __builtin_bit_cast(u16, h);
}

__device__ __forceinline__ void gl_lds16(const void* g, void* l) {
  __builtin_amdgcn_global_load_lds(
      (const __attribute__((address_space(1))) u32*)g,
      (__attribute__((address_space(3))) u32*)l, 16, 0, 0);
}

// ---------------- kernel 1: convert weights fp32 -> fp16 ----------------
__global__ void k_cvt_w(const float* __restrict__ w0, const float* __restrict__ w1,
                        const float* __restrict__ w2, const float* __restrict__ w3,
                        u16* __restrict__ dst) {
  int wsel = blockIdx.y;
  const float* src = wsel == 0 ? w0 : wsel == 1 ? w1 : wsel == 2 ? w2 : w3;
  int i = (blockIdx.x * 256 + threadIdx.x) * 4;
  float4 v = *(const float4*)(src + i);
  ushort4 o;
  o.x = f2h(v.x); o.y = f2h(v.y); o.z = f2h(v.z); o.w = f2h(v.w);
  *(ushort4*)(dst + (size_t)wsel * CCH * CCH + i) = o;
}

// ------------- kernel 2: x (b,c,n) fp32 -> xT (b,n,c) fp16 --------------
__global__ void k_cvt_x(const float* __restrict__ x, u16* __restrict__ xT) {
  __shared__ u16 t[64][66];
  int b = blockIdx.z, c0 = blockIdx.y * 64, n0 = blockIdx.x * 64;
  int col = threadIdx.x & 63, rb = threadIdx.x >> 6;
#pragma unroll
  for (int rr = 0; rr < 16; rr++) {
    int r = rr * 4 + rb;  // c-local
    t[r][col] = f2h(x[((size_t)b * CCH + c0 + r) * NSP + n0 + col]);
  }
  __syncthreads();
#pragma unroll
  for (int rr = 0; rr < 16; rr++) {
    int r = rr * 4 + rb;  // n-local
    xT[((size_t)b * NSP + n0 + r) * CCH + c0 + col] = t[col][r];
  }
}

// ------- kernel 3: fused 4-way projection GEMM (Wq/Wk/Wv/Wsc) ----------
__global__ __launch_bounds__(256) void k_proj(const u16* __restrict__ Wall,
    const u16* __restrict__ xT, u16* __restrict__ Qo, u16* __restrict__ Ko,
    u16* __restrict__ Vo, float* __restrict__ SCo) {
  __shared__ u16 smem[17408];          // A[128][64] | B[128][64]; reused as stash[128][136]
  u16* At = smem;
  u16* Bt = smem + 8192;
  int z = blockIdx.z, b = z >> 2, wsel = z & 3;
  int o0 = blockIdx.y * 128, n0 = blockIdx.x * 128;
  int tid = threadIdx.x, lane = tid & 63, wv = tid >> 6;
  int wr = wv >> 1, wc = wv & 1;
  const u16* Asrc = Wall + (size_t)wsel * CCH * CCH + (size_t)o0 * CCH;
  const u16* Bsrc = xT + ((size_t)b * NSP + n0) * CCH;
  f32x4 acc[4][4] = {};
  for (int kc = 0; kc < CCH; kc += 64) {
    __syncthreads();
#pragma unroll
    for (int i = 0; i < 4; i++) {
      int ch = (wv * 4 + i) * 64 + lane;
      int row = ch >> 3, cc = ch & 7;
      gl_lds16(Asrc + (size_t)row * CCH + kc + ((cc ^ (row & 7)) << 3), At + (wv * 4 + i) * 512);
      gl_lds16(Bsrc + (size_t)row * CCH + kc + ((cc ^ (row & 7)) << 3), Bt + (wv * 4 + i) * 512);
    }
    __syncthreads();
#pragma unroll
    for (int ks = 0; ks < 2; ks++) {
      f16x8 af[4], bfr[4];
#pragma unroll
      for (int f = 0; f < 4; f++) {
        int orow = wr * 64 + f * 16 + (lane & 15);
        int nrow = wc * 64 + f * 16 + (lane & 15);
        int k8 = (lane >> 4) + ks * 4;
        af[f]  = *(const f16x8*)(At + orow * 64 + ((k8 ^ (orow & 7)) << 3));
        bfr[f] = *(const f16x8*)(Bt + nrow * 64 + ((k8 ^ (nrow & 7)) << 3));
      }
#pragma unroll
      for (int i = 0; i < 4; i++)
#pragma unroll
        for (int j = 0; j < 4; j++)
          acc[i][j] = __builtin_amdgcn_mfma_f32_16x16x32_f16(af[i], bfr[j], acc[i][j], 0, 0, 0);
    }
  }
  if (wsel >= 2) {
#pragma unroll
    for (int i = 0; i < 4; i++)
#pragma unroll
      for (int j = 0; j < 4; j++)
#pragma unroll
        for (int r = 0; r < 4; r++) {
          int o = o0 + wr * 64 + i * 16 + ((lane >> 4) << 2) + r;
          int n = n0 + wc * 64 + j * 16 + (lane & 15);
          size_t idx = ((size_t)b * CCH + o) * NSP + n;
          if (wsel == 3) SCo[idx] = acc[i][j][r];
          else           Vo[idx]  = f2h(acc[i][j][r]);
        }
  } else {
    __syncthreads();
    u16* stash = smem;  // [128 n][136 o]
#pragma unroll
    for (int i = 0; i < 4; i++)
#pragma unroll
      for (int j = 0; j < 4; j++)
#pragma unroll
        for (int r = 0; r < 4; r++) {
          int ol = wr * 64 + i * 16 + ((lane >> 4) << 2) + r;
          int nl = wc * 64 + j * 16 + (lane & 15);
          stash[nl * 136 + ol] = f2h(acc[i][j][r]);
        }
    __syncthreads();
    u16* dst = wsel ? Ko : Qo;
    int hl = tid >> 7, nn = tid & 127;
    int h = (o0 >> 6) + hl;
    size_t base = ((size_t)(b * HEADS + h) * NSP + n0 + nn) * DH;
#pragma unroll
    for (int c2 = 0; c2 < 8; c2++)
      *(int4*)(dst + base + c2 * 8) = *(const int4*)(stash + nn * 136 + hl * 64 + c2 * 8);
  }
}

// ------------------- kernel 4: flash attention + epilogue ---------------
// block = (q-64-tile, b*8+h): 2 waves x 32 q-rows. KV in 64-m tiles,
// double-buffered LDS, one barrier per tile. Swapped QK^T (32x32 MFMA),
// softmax + P->A-frag fully in-register, defer-max THR=8.
__device__ __forceinline__ void stage_kv(const u16* Ksrc, const u16* Vsrc,
                                         u16* Kb, u16* Vb, int bsel, int m0, int tid) {
#pragma unroll
  for (int i = 0; i < 4; i++) {
    int ch = i * 128 + tid;
    int row = ch >> 3, cc = ch & 7;
    gl_lds16(Ksrc + (size_t)(m0 + row) * DH + ((cc ^ (row & 7)) << 3),
             Kb + bsel * 4096 + ch * 8);
    gl_lds16(Vsrc + (size_t)row * NSP + m0 + ((cc ^ (row & 7)) << 3),
             Vb + bsel * 4096 + ch * 8);
  }
}

__global__ __launch_bounds__(128) void k_attn(const u16* __restrict__ Qw,
    const u16* __restrict__ Kw, const u16* __restrict__ Vw,
    const float* __restrict__ gamma, float* __restrict__ out) {
  __shared__ u16 smem[16384];          // Kbuf[2][64][64] | Vbuf[2][64][64]
  u16* Kb = smem;
  u16* Vb = smem + 8192;
  int qt = blockIdx.x, bh = blockIdx.y;
  int b = bh >> 3, h = bh & 7;
  int tid = threadIdx.x, lane = tid & 63, wv = tid >> 6;
  int l31 = lane & 31, hi = lane >> 5;
  int q0w = qt * 64 + wv * 32;
  const u16* Ksrc = Kw + (size_t)bh * NSP * DH;
  const u16* Vsrc = Vw + ((size_t)b * CCH + h * DH) * NSP;

  // Q B-frags: lane holds Q[q0w + l31][d = 16*kd + 8*hi + j]
  f16x8 qf[4];
  const u16* Qbase = Qw + ((size_t)bh * NSP + q0w + l31) * DH + hi * 8;
#pragma unroll
  for (int kd = 0; kd < 4; kd++)
    qf[kd] = *(const f16x8*)(Qbase + kd * 16);

  float mrun = -1e30f, lrun = 0.f;
  f32x16 acc0 = {}, acc1 = {};       // O for d-blocks 0,1; lane: d = dblk*32+l31, q = (r&3)+8*(r>>2)+4*hi

  stage_kv(Ksrc, Vsrc, Kb, Vb, 0, 0, tid);
  __syncthreads();

  for (int mt = 0; mt < NSP / 64; mt++) {
    int cur = mt & 1;
    if (mt + 1 < NSP / 64) stage_kv(Ksrc, Vsrc, Kb, Vb, cur ^ 1, (mt + 1) * 64, tid);

    // ---- S^T = K Q^T : 2 m-blocks x 4 d-steps of 32x32x16 ----
    f32x16 s0 = {}, s1 = {};
#pragma unroll
    for (int kd = 0; kd < 4; kd++) {
      int cc = 2 * kd + hi;
      int r0 = l31, r1 = 32 + l31;
      f16x8 k0 = *(const f16x8*)(Kb + cur * 4096 + r0 * 64 + ((cc ^ (r0 & 7)) << 3));
      f16x8 k1 = *(const f16x8*)(Kb + cur * 4096 + r1 * 64 + ((cc ^ (r1 & 7)) << 3));
      s0 = __builtin_amdgcn_mfma_f32_32x32x16_f16(k0, qf[kd], s0, 0, 0, 0);
      s1 = __builtin_amdgcn_mfma_f32_32x32x16_f16(k1, qf[kd], s1, 0, 0, 0);
    }

    // ---- online softmax, q = l31 per lane ----
    float tm = fmaxf(s0[0], s1[0]);
#pragma unroll
    for (int r = 1; r < 16; r++) tm = fmaxf(tm, fmaxf(s0[r], s1[r]));
    tm = fmaxf(tm, __shfl_xor(tm, 32));
    if (__any(tm > mrun + 8.0f)) {            // rescale (rare after first tile)
      float mnew = fmaxf(mrun, tm);
      float scl = __expf(mrun - mnew);
      mrun = mnew;
      lrun *= scl;
#pragma unroll
      for (int r = 0; r < 16; r++) {
        float sq = __shfl(scl, (r & 3) + 8 * (r >> 2) + 4 * hi);
        acc0[r] *= sq;
        acc1[r] *= sq;
      }
    }
    float ts = 0.f;
    u32 P2[2][4][2];                           // [m-blk][s2][c]; halves m32 = 4hi+8*s2+2c+{0,1}
#pragma unroll
    for (int s2 = 0; s2 < 4; s2++)
#pragma unroll
      for (int c = 0; c < 2; c++) {
        float a0 = __expf(s0[4 * s2 + 2 * c] - mrun);
        float b0 = __expf(s0[4 * s2 + 2 * c + 1] - mrun);
        float a1 = __expf(s1[4 * s2 + 2 * c] - mrun);
        float b1 = __expf(s1[4 * s2 + 2 * c + 1] - mrun);
        ts += (a0 + b0) + (a1 + b1);
        P2[0][s2][c] = __builtin_bit_cast(u32, __builtin_amdgcn_cvt_pkrtz(a0, b0));
        P2[1][s2][c] = __builtin_bit_cast(u32, __builtin_amdgcn_cvt_pkrtz(a1, b1));
      }
    ts += __shfl_xor(ts, 32);
    lrun += ts;

    // ---- O += P V : build A-frags in-register, 2 d-blocks x 4 m-steps ----
#pragma unroll
    for (int s = 0; s < 4; s++) {              // m in [16s, 16s+16)
      int blk = s >> 1, par = s & 1;
      int T[4];
#pragma unroll
      for (int c = 0; c < 2; c++) {
        int x = (int)P2[blk][2 * par][c];      // own half
        int y = (int)P2[blk][2 * par + 1][c];  // partner's half
        int xs = __shfl_xor(x, 32);
        int ys = __shfl_xor(y, 32);
        T[c]     = hi ? ys : x;                // k = 8hi + 2c + {0,1}
        T[c + 2] = hi ? y  : xs;               // k = 8hi + 4 + 2c + {0,1}
      }
      f16x8 pa = __builtin_bit_cast(f16x8, (i32x4){T[0], T[1], T[2], T[3]});
      int ccv = 2 * s + hi;
      {
        int row = l31;
        f16x8 vb = *(const f16x8*)(Vb + cur * 4096 + row * 64 + ((ccv ^ (row & 7)) << 3));
        acc0 = __builtin_amdgcn_mfma_f32_32x32x16_f16(pa, vb, acc0, 0, 0, 0);
      }
      {
        int row = 32 + l31;
        f16x8 vb = *(const f16x8*)(Vb + cur * 4096 + row * 64 + ((ccv ^ (row & 7)) << 3));
        acc1 = __builtin_amdgcn_mfma_f32_32x32x16_f16(pa, vb, acc1, 0, 0, 0);
      }
    }
    __syncthreads();
  }

  // ---- epilogue: out = gamma * O / l + SC (RMW), direct from regs ----
  float inv = 1.0f / lrun;
  float invq[16];
#pragma unroll
  for (int r = 0; r < 16; r++)
    invq[r] = __shfl(inv, (r & 3) + 8 * (r >> 2) + 4 * hi);
  size_t outbase = ((size_t)b * CCH + h * DH) * NSP;
#pragma unroll
  for (int dblk = 0; dblk < 2; dblk++) {
    int d = dblk * 32 + l31;
    float g = gamma[h * DH + d];
    float* orow = out + outbase + (size_t)d * NSP + q0w;
#pragma unroll
    for (int s2 = 0; s2 < 4; s2++) {
      int n = 8 * s2 + 4 * hi;
      f32x4 o;
#pragma unroll
      for (int t = 0; t < 4; t++) {
        int r = 4 * s2 + t;
        float a = dblk ? acc1[r] : acc0[r];
        o[t] = a * invq[r] * g;
      }
      f32x4 sc = *(const f32x4*)(orow + n);
      *(f32x4*)(orow + n) = o + sc;
    }
  }
}

extern "C" void kernel_launch(void* const* d_in, const int* in_sizes, int n_in,
                              void* d_out, int out_size, void* d_ws, size_t ws_size,
                              hipStream_t stream) {
  const float* x     = (const float*)d_in[0];
  const float* Wq    = (const float*)d_in[1];
  const float* Wk    = (const float*)d_in[2];
  const float* Wv    = (const float*)d_in[3];
  const float* Wsc   = (const float*)d_in[4];
  const float* gamma = (const float*)d_in[5];
  float* out = (float*)d_out;

  u16* xT   = (u16*)d_ws;                               // 4*2304*512
  u16* Wall = xT + (size_t)BSZ * NSP * CCH;             // 4*512*512
  u16* Qw   = Wall + (size_t)4 * CCH * CCH;             // 4*8*2304*64
  u16* Kw   = Qw + (size_t)BSZ * CCH * NSP;
  u16* Vw   = Kw + (size_t)BSZ * CCH * NSP;

  hipLaunchKernelGGL(k_cvt_w, dim3(CCH * CCH / 1024, 4), dim3(256), 0, stream,
                     Wq, Wk, Wv, Wsc, Wall);
  hipLaunchKernelGGL(k_cvt_x, dim3(NSP / 64, CCH / 64, BSZ), dim3(256), 0, stream, x, xT);
  hipLaunchKernelGGL(k_proj, dim3(NSP / 128, CCH / 128, BSZ * 4), dim3(256), 0, stream,
                     Wall, xT, Qw, Kw, Vw, out);
  hipLaunchKernelGGL(k_attn, dim3(NSP / 64, BSZ * HEADS), dim3(128), 0, stream,
                     Qw, Kw, Vw, gamma, out);
}